// Round 10
// baseline (258.355 us; speedup 1.0000x reference)
//
#include <hip/hip_runtime.h>
#include <math.h>

#define N_POS 8000
#define NSPLIT 10

typedef __bf16 bf16x8 __attribute__((ext_vector_type(8)));
typedef float  f32x4  __attribute__((ext_vector_type(4)));

#define MFMA(a,b,c) __builtin_amdgcn_mfma_f32_16x16x32_bf16((a),(b),(c),0,0,0)

// MFMA 16x16x32 lane layouts (verified m89/m120):
//   A[m][k]: m = lane&15, k = (lane>>4)*8 + j
//   B[k][n]: n = lane&15, k = (lane>>4)*8 + j
//   D[m][n]: n = lane&15, m = (lane>>4)*4 + reg

#define GLOAD_LDS(gp, lp) \
    __builtin_amdgcn_global_load_lds( \
        (const __attribute__((address_space(1))) void*)(gp), \
        (__attribute__((address_space(3))) void*)(lp), 16, 0, 0)

// ---------------------------------------------------------------------------
// Kernel A: QKV projections via MFMA. grid 500: nt = bx>>1 (32-n tile),
// h = bx&1 -> mtiles h*5..h*5+4.  (R4-verified kernel + bn_stats zero-init.)
// q_bf,k_bf: [n][16] bf16.  v_bf: [c][8000] bf16.
// ---------------------------------------------------------------------------
__global__ __launch_bounds__(256) void qkv_kernel(
    const float* __restrict__ x,
    const float* __restrict__ wq, const float* __restrict__ bq,
    const float* __restrict__ wk, const float* __restrict__ bk,
    const float* __restrict__ wv, const float* __restrict__ bv,
    __bf16* __restrict__ q_bf, __bf16* __restrict__ k_bf, __bf16* __restrict__ v_bf,
    float* __restrict__ bn_stats)
{
    __shared__ __bf16 x_lds[32 * 136];          // [n][c]
    __shared__ __bf16 v_out[80 * 36];           // [local v-ch][n]

    const int t    = threadIdx.x;
    const int nt   = blockIdx.x >> 1;
    const int h    = blockIdx.x & 1;
    const int n0   = nt * 32;
    const int lane = t & 63;
    const int w    = t >> 6;
    const int l15  = lane & 15;
    const int quad = lane >> 4;

    if (blockIdx.x == 0) bn_stats[t] = 0.f;   // bn_sum[128] + bn_sumsq[128]

    // stage x tile [128c x 32n] fp32 -> x_lds[n][c] bf16 (transpose+convert)
    for (int r = 0; r < 4; ++r) {
        int f = r * 256 + t;
        int ch = f >> 3, n4 = f & 7;
        float4 xv = *reinterpret_cast<const float4*>(&x[ch * N_POS + n0 + n4 * 4]);
        x_lds[(n4 * 4 + 0) * 136 + ch] = (__bf16)xv.x;
        x_lds[(n4 * 4 + 1) * 136 + ch] = (__bf16)xv.y;
        x_lds[(n4 * 4 + 2) * 136 + ch] = (__bf16)xv.z;
        x_lds[(n4 * 4 + 3) * 136 + ch] = (__bf16)xv.w;
    }

    // A-frags: wave w owns mtiles {h*5+w, h*5+4 (w==0 only)}
    const int nmt = (w == 0) ? 2 : 1;
    int mts[2] = { h * 5 + w, h * 5 + 4 };

    bf16x8 aw[2][4];
    f32x4  acc[2][2];
    for (int mi = 0; mi < nmt; ++mi) {
        int mt = mts[mi];
        const float *wrow, *brow;
        if (mt == 0)      { wrow = wq + l15 * 128;               brow = bq; }
        else if (mt == 1) { wrow = wk + l15 * 128;               brow = bk; }
        else              { wrow = wv + ((mt - 2) * 16 + l15) * 128;
                            brow = bv + (mt - 2) * 16; }
        for (int ks = 0; ks < 4; ++ks) {
            float4 f0 = *reinterpret_cast<const float4*>(wrow + ks * 32 + quad * 8);
            float4 f1 = *reinterpret_cast<const float4*>(wrow + ks * 32 + quad * 8 + 4);
            bf16x8 a;
            a[0]=(__bf16)f0.x; a[1]=(__bf16)f0.y; a[2]=(__bf16)f0.z; a[3]=(__bf16)f0.w;
            a[4]=(__bf16)f1.x; a[5]=(__bf16)f1.y; a[6]=(__bf16)f1.z; a[7]=(__bf16)f1.w;
            aw[mi][ks] = a;
        }
        for (int ni = 0; ni < 2; ++ni) {
            acc[mi][ni][0] = brow[quad * 4 + 0]; acc[mi][ni][1] = brow[quad * 4 + 1];
            acc[mi][ni][2] = brow[quad * 4 + 2]; acc[mi][ni][3] = brow[quad * 4 + 3];
        }
    }
    __syncthreads();

    for (int ks = 0; ks < 4; ++ks) {
        bf16x8 b0 = *reinterpret_cast<const bf16x8*>(&x_lds[(0  + l15) * 136 + ks * 32 + quad * 8]);
        bf16x8 b1 = *reinterpret_cast<const bf16x8*>(&x_lds[(16 + l15) * 136 + ks * 32 + quad * 8]);
        for (int mi = 0; mi < nmt; ++mi) {
            acc[mi][0] = MFMA(aw[mi][ks], b0, acc[mi][0]);
            acc[mi][1] = MFMA(aw[mi][ks], b1, acc[mi][1]);
        }
    }

    union S4 { short4 s; __bf16 b[4]; };
    for (int mi = 0; mi < nmt; ++mi) {
        int mt = mts[mi];
        for (int ni = 0; ni < 2; ++ni) {
            S4 u;
            u.b[0]=(__bf16)acc[mi][ni][0]; u.b[1]=(__bf16)acc[mi][ni][1];
            u.b[2]=(__bf16)acc[mi][ni][2]; u.b[3]=(__bf16)acc[mi][ni][3];
            int n = n0 + ni * 16 + l15;
            if (mt == 0) {
                *reinterpret_cast<short4*>(&q_bf[n * 16 + quad * 4]) = u.s;
            } else if (mt == 1) {
                *reinterpret_cast<short4*>(&k_bf[n * 16 + quad * 4]) = u.s;
            } else {
                int lv = (mt - 2) * 16 - h * 48 + quad * 4;
                int nl = ni * 16 + l15;
                v_out[(lv + 0) * 36 + nl] = u.b[0];
                v_out[(lv + 1) * 36 + nl] = u.b[1];
                v_out[(lv + 2) * 36 + nl] = u.b[2];
                v_out[(lv + 3) * 36 + nl] = u.b[3];
            }
        }
    }
    __syncthreads();
    const int nch = h ? 80 : 48;
    for (int f = t; f < nch * 8; f += 256) {
        int lc = f >> 3, n4 = f & 7;
        int2 d = *reinterpret_cast<const int2*>(&v_out[lc * 36 + n4 * 4]);
        *reinterpret_cast<int2*>(&v_bf[(lc + h * 48) * N_POS + n0 + n4 * 4]) = d;
    }
}

// ---------------------------------------------------------------------------
// Kernel B: fused attention, split-K, MFMA, global_load_lds double-buffer.
// BYTE-EXACT R9 kernel (measured 54us, passed) with ONE change: av_part is
// bf16 (epilogue converts acc to bf16 short4; same indices as R9's fp32).
// grid = 250*nsplit.
// ---------------------------------------------------------------------------
__global__ __launch_bounds__(256, 4) void attn_kernel(
    const __bf16* __restrict__ q_bf, const __bf16* __restrict__ k_bf,
    const __bf16* __restrict__ v_bf, __bf16* __restrict__ av_part,
    float* __restrict__ l_part, int nsplit)
{
    __shared__ __bf16 v_buf[2][8192];   // 16 KB each
    __shared__ __bf16 k_buf[2][1024];   // 2 KB each
    __shared__ __bf16 p_lds[2048];      // 4 KB;  total = 40960 B -> 4 blocks/CU

    const int t    = threadIdx.x;
    const int qt   = blockIdx.x % 250;
    const int sp   = blockIdx.x / 250;
    const int n0q  = qt * 32;
    const int lane = t & 63;
    const int w    = t >> 6;
    const int l15  = lane & 15;
    const int quad = lane >> 4;

    // staging maps (per lane, loop-invariant)
    const int chL   = lane >> 3;              // V: low 3 bits of channel
    const int vpart = (lane & 7) ^ chL;       // V: key-octet (XOR swizzle)
    const int kkey  = lane >> 1;              // K: key within 32-key half
    const int khalf = lane & 1;               // K: dim half

    // Q B-frags in registers (k-dim 16 padded to 32 with zeros)
    bf16x8 aq[2];
    for (int ni = 0; ni < 2; ++ni) {
        for (int j = 0; j < 8; ++j) aq[ni][j] = (__bf16)0.0f;
        if (quad < 2)
            aq[ni] = *reinterpret_cast<const bf16x8*>(
                &q_bf[(n0q + ni * 16 + l15) * 16 + quad * 8]);
    }
    bf16x8 ones;
    for (int j = 0; j < 8; ++j) ones[j] = (__bf16)1.0f;

    f32x4 acc[2][2];
    for (int mi = 0; mi < 2; ++mi)
        for (int ni = 0; ni < 2; ++ni)
            for (int r = 0; r < 4; ++r) acc[mi][ni][r] = 0.f;
    f32x4 lacc[2];
    for (int ni = 0; ni < 2; ++ni)
        for (int r = 0; r < 4; ++r) lacc[ni][r] = 0.f;

    const int base = 125 / nsplit, rem = 125 - base * nsplit;
    const int kt0  = sp * base + (sp < rem ? sp : rem);
    const int cnt  = base + (sp < rem ? 1 : 0);

    // issue one tile's staging DMA: 4 V ops (wave-split) + 2 K ops
    auto stage = [&](int kt, int buf) {
        const int n0k = kt * 64;
        for (int r = 0; r < 4; ++r) {
            int R = w * 4 + r;   // wave-uniform LDS base
            GLOAD_LDS(v_bf + (8 * R + chL) * N_POS + n0k + vpart * 8,
                      &v_buf[buf][R * 512]);
        }
        for (int h = 0; h < 2; ++h) {
            GLOAD_LDS(k_bf + (size_t)(n0k + h * 32 + kkey) * 16 + khalf * 8,
                      &k_buf[buf][h * 512]);
        }
    };

    stage(kt0, 0);

    const int oS  = w * 2 + (quad >> 1);   // P-write octet
    const int sub = (quad & 1) * 4;        // P-write elem offset in chunk

    for (int it = 0; it < cnt; ++it) {
        const int kt  = kt0 + it;
        const int cur = it & 1;
        __syncthreads();   // barrier_A: cur DMA drained; prev PV reads done

        // ---- S phase: A = K rows (wave w -> keys w*16..+15), B = Q regs
        bf16x8 ak;
        for (int j = 0; j < 8; ++j) ak[j] = (__bf16)0.0f;
        if (quad < 2)
            ak = *reinterpret_cast<const bf16x8*>(
                &k_buf[cur][(w * 16 + l15) * 16 + quad * 8]);
        f32x4 s0, s1;
        for (int r = 0; r < 4; ++r) { s0[r] = 0.f; s1[r] = 0.f; }
        s0 = MFMA(ak, aq[0], s0);   // D[m=key][n=q]
        s1 = MFMA(ak, aq[1], s1);
        union SH { short4 sh; __bf16 b[4]; };
        {
            SH u;
            u.b[0] = (__bf16)__expf(s0[0]); u.b[1] = (__bf16)__expf(s0[1]);
            u.b[2] = (__bf16)__expf(s0[2]); u.b[3] = (__bf16)__expf(s0[3]);
            *reinterpret_cast<short4*>(&p_lds[(oS * 32 + l15) * 8 + sub]) = u.sh;
            u.b[0] = (__bf16)__expf(s1[0]); u.b[1] = (__bf16)__expf(s1[1]);
            u.b[2] = (__bf16)__expf(s1[2]); u.b[3] = (__bf16)__expf(s1[3]);
            *reinterpret_cast<short4*>(&p_lds[(oS * 32 + 16 + l15) * 8 + sub]) = u.sh;
        }
        __syncthreads();   // barrier_B: P visible; nothing outstanding -> cheap

        // ---- issue next tile's DMA (drains at next barrier_A, hidden under PV)
        if (it + 1 < cnt) stage(kt + 1, cur ^ 1);

        // ---- PV phase: wave w owns ch-tiles {2w, 2w+1}
        const int chl = l15 & 7;
        for (int ks = 0; ks < 2; ++ks) {
            int pz = ((ks * 4 + quad) ^ chl);
            bf16x8 a0 = *reinterpret_cast<const bf16x8*>(
                &v_buf[cur][(((2 * w)     * 2 + (l15 >> 3)) * 64 + chl * 8 + pz) * 8]);
            bf16x8 a1 = *reinterpret_cast<const bf16x8*>(
                &v_buf[cur][(((2 * w + 1) * 2 + (l15 >> 3)) * 64 + chl * 8 + pz) * 8]);
            bf16x8 p0 = *reinterpret_cast<const bf16x8*>(
                &p_lds[((ks * 4 + quad) * 32 + 0  + l15) * 8]);
            bf16x8 p1 = *reinterpret_cast<const bf16x8*>(
                &p_lds[((ks * 4 + quad) * 32 + 16 + l15) * 8]);
            acc[0][0] = MFMA(a0, p0, acc[0][0]);
            acc[0][1] = MFMA(a0, p1, acc[0][1]);
            acc[1][0] = MFMA(a1, p0, acc[1][0]);
            acc[1][1] = MFMA(a1, p1, acc[1][1]);
            if (w == 0) {
                lacc[0] = MFMA(ones, p0, lacc[0]);
                lacc[1] = MFMA(ones, p1, lacc[1]);
            }
        }
    }

    // write av partials (bf16): av_part[sp][n][c]; indices identical to R9 fp32
    __bf16* dst = av_part + (size_t)sp * 1024000;
    union SO { short4 sh; __bf16 b[4]; };
    for (int mi = 0; mi < 2; ++mi)
        for (int ni = 0; ni < 2; ++ni) {
            SO o;
            o.b[0] = (__bf16)acc[mi][ni][0]; o.b[1] = (__bf16)acc[mi][ni][1];
            o.b[2] = (__bf16)acc[mi][ni][2]; o.b[3] = (__bf16)acc[mi][ni][3];
            *reinterpret_cast<short4*>(
                &dst[(size_t)(n0q + ni * 16 + l15) * 128 + (2 * w + mi) * 16 + quad * 4]) = o.sh;
        }
    if (w == 0 && quad == 0) {
        l_part[sp * N_POS + n0q + 0  + l15] = lacc[0][0];
        l_part[sp * N_POS + n0q + 16 + l15] = lacc[1][0];
    }
}

// ---------------------------------------------------------------------------
// Kernel C: split-K reduce + normalize (fp32) fused with y = wa@av + ba (MFMA)
// + BN stats.  R7-verified kernel (n-tiles of 16, pad-17 b_lds). grid 500.
// ---------------------------------------------------------------------------
__global__ __launch_bounds__(256) void proj_out_kernel(
    const __bf16* __restrict__ av_part, const float* __restrict__ l_part,
    const float* __restrict__ wa, const float* __restrict__ ba,
    float* __restrict__ y_ws, float* __restrict__ bn_sum, float* __restrict__ bn_sumsq,
    int nsplit)
{
    __shared__ __bf16 b_lds[4352];   // (16 oc * 17 + 16) chunks * 8 elems

    const int t    = threadIdx.x;
    const int n0   = blockIdx.x * 16;
    const int lane = t & 63;
    const int w    = t >> 6;
    const int l15  = lane & 15;
    const int quad = lane >> 4;

    // build normalized B tile: 256 c-octets, 1 per thread (1KB-contig reads)
    {
        int n = t >> 4, oc = t & 15;
        float l = 0.f;
        for (int s = 0; s < nsplit; ++s) l += l_part[s * N_POS + n0 + n];
        float sum[8];
#pragma unroll
        for (int i = 0; i < 8; ++i) sum[i] = 0.f;
        for (int s = 0; s < nsplit; ++s) {
            bf16x8 p = *reinterpret_cast<const bf16x8*>(
                &av_part[(size_t)s * 1024000 + (size_t)(n0 + n) * 128 + oc * 8]);
#pragma unroll
            for (int i = 0; i < 8; ++i) sum[i] += (float)p[i];
        }
        float inv = 1.f / l;
        union { int4 iv; __bf16 b[8]; } u;
#pragma unroll
        for (int i = 0; i < 8; ++i) u.b[i] = (__bf16)(sum[i] * inv);
        *reinterpret_cast<int4*>(&b_lds[(oc * 17 + n) * 8]) = u.iv;
    }

    // A-frags: wa rows for mtiles {2w, 2w+1}
    bf16x8 aw[2][4];
    f32x4  acc[2];
    for (int mi = 0; mi < 2; ++mi) {
        int mt = 2 * w + mi;
        const float* wrow = wa + (mt * 16 + l15) * 128;
        for (int ks = 0; ks < 4; ++ks) {
            float4 f0 = *reinterpret_cast<const float4*>(wrow + ks * 32 + quad * 8);
            float4 f1 = *reinterpret_cast<const float4*>(wrow + ks * 32 + quad * 8 + 4);
            bf16x8 a;
            a[0]=(__bf16)f0.x; a[1]=(__bf16)f0.y; a[2]=(__bf16)f0.z; a[3]=(__bf16)f0.w;
            a[4]=(__bf16)f1.x; a[5]=(__bf16)f1.y; a[6]=(__bf16)f1.z; a[7]=(__bf16)f1.w;
            aw[mi][ks] = a;
        }
        acc[mi][0] = ba[mt * 16 + quad * 4 + 0];
        acc[mi][1] = ba[mt * 16 + quad * 4 + 1];
        acc[mi][2] = ba[mt * 16 + quad * 4 + 2];
        acc[mi][3] = ba[mt * 16 + quad * 4 + 3];
    }
    __syncthreads();

    for (int ks = 0; ks < 4; ++ks) {
        bf16x8 b = *reinterpret_cast<const bf16x8*>(
            &b_lds[((ks * 4 + quad) * 17 + l15) * 8]);
        acc[0] = MFMA(aw[0][ks], b, acc[0]);
        acc[1] = MFMA(aw[1][ks], b, acc[1]);
    }

    // y writes [c][n] + BN partial stats
    for (int mi = 0; mi < 2; ++mi) {
#pragma unroll
        for (int r = 0; r < 4; ++r) {
            int ch = (2 * w + mi) * 16 + quad * 4 + r;
            float v = acc[mi][r];
            y_ws[ch * N_POS + n0 + l15] = v;
            float s1 = v, s2 = v * v;
#pragma unroll
            for (int off = 8; off >= 1; off >>= 1) {
                s1 += __shfl_xor(s1, off, 64);
                s2 += __shfl_xor(s2, off, 64);
            }
            if (l15 == 0) {
                atomicAdd(&bn_sum[ch],   s1);
                atomicAdd(&bn_sumsq[ch], s2);
            }
        }
    }
}

// ---------------------------------------------------------------------------
// Kernel D: BatchNorm (training stats) + ReLU + residual. grid 1000, block 256.
// ---------------------------------------------------------------------------
__global__ __launch_bounds__(256) void bn_relu_kernel(
    const float* __restrict__ y_ws, const float* __restrict__ x,
    const float* __restrict__ bn_sum, const float* __restrict__ bn_sumsq,
    const float* __restrict__ bn_w, const float* __restrict__ bn_b,
    float* __restrict__ out)
{
    const int i4 = blockIdx.x * 256 + threadIdx.x;
    const int c  = i4 / 2000;
    const float mean  = bn_sum[c]   * (1.f / 8000.f);
    const float var   = bn_sumsq[c] * (1.f / 8000.f) - mean * mean;
    const float rstd  = rsqrtf(var + 1e-5f);
    const float scale = bn_w[c] * rstd;
    const float shift = bn_b[c] - mean * scale;

    float4 y4 = reinterpret_cast<const float4*>(y_ws)[i4];
    float4 x4 = reinterpret_cast<const float4*>(x)[i4];
    float4 o4;
    o4.x = fmaxf(y4.x * scale + shift, 0.f) + x4.x;
    o4.y = fmaxf(y4.y * scale + shift, 0.f) + x4.y;
    o4.z = fmaxf(y4.z * scale + shift, 0.f) + x4.z;
    o4.w = fmaxf(y4.w * scale + shift, 0.f) + x4.w;
    reinterpret_cast<float4*>(out)[i4] = o4;
}

// ---------------------------------------------------------------------------
extern "C" void kernel_launch(void* const* d_in, const int* in_sizes, int n_in,
                              void* d_out, int out_size, void* d_ws, size_t ws_size,
                              hipStream_t stream)
{
    const float* x    = (const float*)d_in[0];
    const float* wq   = (const float*)d_in[1];
    const float* bq   = (const float*)d_in[2];
    const float* wk   = (const float*)d_in[3];
    const float* bk   = (const float*)d_in[4];
    const float* wv   = (const float*)d_in[5];
    const float* bv   = (const float*)d_in[6];
    const float* wa   = (const float*)d_in[7];
    const float* ba   = (const float*)d_in[8];
    const float* bn_w = (const float*)d_in[9];
    const float* bn_b = (const float*)d_in[10];
    float* out = (float*)d_out;

    char* base = (char*)d_ws;
    // byte layout (27,457,024 B total; ws evidence >= 58.6 MB from R7):
    __bf16* av_part = (__bf16*)base;                   // 20,480,000 B (10 x 8000 x 128 bf16)
    __bf16* q_bf    = (__bf16*)(base + 20480000);      //    256,000 B
    __bf16* k_bf    = (__bf16*)(base + 20736000);      //    256,000 B
    __bf16* v_bf    = (__bf16*)(base + 20992000);      //  2,048,000 B
    float*  l_part  = (float*)(base + 23040000);       //    320,000 B
    float*  bn_sum   = (float*)(base + 23360000);      //        512 B
    float*  bn_sumsq = bn_sum + 128;                   //        512 B
    float*  y_ws    = (float*)(base + 23361024);       //  4,096,000 B

    qkv_kernel<<<500, 256, 0, stream>>>(x, wq, bq, wk, bk, wv, bv,
                                        q_bf, k_bf, v_bf, bn_sum);
    attn_kernel<<<250 * NSPLIT, 256, 0, stream>>>(q_bf, k_bf, v_bf,
                                                  av_part, l_part, NSPLIT);
    proj_out_kernel<<<500, 256, 0, stream>>>(av_part, l_part, wa, ba,
                                             y_ws, bn_sum, bn_sumsq, NSPLIT);
    bn_relu_kernel<<<1000, 256, 0, stream>>>(y_ws, x, bn_sum, bn_sumsq,
                                             bn_w, bn_b, out);
}